// Round 1
// baseline (3766.446 us; speedup 1.0000x reference)
//
#include <hip/hip_runtime.h>
#include <math.h>

#define BB 4
#define SS 2048
#define INDIM 4
#define DD 128
#define HH 8
#define DH 16
#define DEPTH 6
#define BUCKET 64
#define NHASH 8
#define NBK 32                 // buckets per hash round
#define DFF 512
#define LL (NHASH*SS)          // 16384 per (b,h)
#define NCHUNK (NHASH*NBK)     // 256 chunks per (b,h)
#define NBH (BB*HH)            // 32

// ---------------- embedding: h = x @ embW + embb ----------------
__global__ void k_embed(const float* __restrict__ x, const float* __restrict__ W,
                        const float* __restrict__ b, float* __restrict__ h) {
    int idx = blockIdx.x * blockDim.x + threadIdx.x;   // B*S*D
    if (idx >= BB*SS*DD) return;
    int d = idx % DD, bs = idx / DD;
    const float* xr = x + bs*INDIM;
    float acc = b[d];
    #pragma unroll
    for (int k = 0; k < INDIM; k++) acc += xr[k] * W[k*DD + d];
    h[idx] = acc;
}

// ---------------- layernorm: one 64-thread wave per row ----------------
__global__ void k_layernorm(const float* __restrict__ in, const float* __restrict__ g,
                            const float* __restrict__ b, float* __restrict__ out) {
    int row = blockIdx.x;                 // B*S rows
    int t = threadIdx.x;                  // 64 threads
    const float* xr = in + (size_t)row*DD;
    float x0 = xr[t], x1 = xr[t+64];
    float s = x0 + x1;
    #pragma unroll
    for (int o = 32; o >= 1; o >>= 1) s += __shfl_xor(s, o);
    float m = s * (1.0f/128.0f);
    float d0 = x0 - m, d1 = x1 - m;
    float vs = d0*d0 + d1*d1;
    #pragma unroll
    for (int o = 32; o >= 1; o >>= 1) vs += __shfl_xor(vs, o);
    float inv = 1.0f / sqrtf(vs * (1.0f/128.0f) + 1e-5f);
    out[(size_t)row*DD + t]      = d0*inv*g[t]    + b[t];
    out[(size_t)row*DD + t + 64] = d1*inv*g[t+64] + b[t+64];
}

// ---------------- qk & v projections (write [b,h,s,dh] layout) ----------------
__global__ void k_proj_qkv(const float* __restrict__ ln, const float* __restrict__ Wqk,
                           const float* __restrict__ Wv, float* __restrict__ qk,
                           float* __restrict__ v) {
    int idx = blockIdx.x * blockDim.x + threadIdx.x;   // B*S*D
    if (idx >= BB*SS*DD) return;
    int n = idx % DD, bs = idx / DD;
    int s = bs % SS, b = bs / SS;
    const float* a = ln + (size_t)bs*DD;
    float acc0 = 0.f, acc1 = 0.f;
    #pragma unroll 4
    for (int k = 0; k < DD; k++) {
        float av = a[k];
        acc0 += av * Wqk[k*DD + n];
        acc1 += av * Wv[k*DD + n];
    }
    int h_ = n >> 4, d_ = n & 15;
    size_t o = (((size_t)(b*HH + h_))*SS + s)*DH + d_;
    qk[o] = acc0; v[o] = acc1;
}

// ---------------- LSH hashing: argmax over [xR; -xR] ----------------
__global__ void k_hash(const float* __restrict__ qk, const float* __restrict__ R,
                       int* __restrict__ bkt) {
    int idx = blockIdx.x * blockDim.x + threadIdx.x;   // B*H*NHASH*S
    if (idx >= NBH*NHASH*SS) return;
    int s = idx % SS; int t = idx / SS;
    int n = t % NHASH; int bh = t / NHASH; int h_ = bh % HH;
    const float* q = qk + (((size_t)bh)*SS + s)*DH;
    float qr[DH];
    #pragma unroll
    for (int d = 0; d < DH; d++) qr[d] = q[d];
    float rxv[16];
    #pragma unroll
    for (int r = 0; r < 16; r++) {
        float acc = 0.f;
        #pragma unroll
        for (int d = 0; d < DH; d++)
            acc += qr[d] * R[((h_*DH + d)*NHASH + n)*16 + r];
        rxv[r] = acc;
    }
    float best = -3.4e38f; int bi = 0;
    #pragma unroll
    for (int j = 0; j < 16; j++) if (rxv[j]  > best) { best = rxv[j];  bi = j; }
    #pragma unroll
    for (int j = 0; j < 16; j++) if (-rxv[j] > best) { best = -rxv[j]; bi = 16 + j; }
    bkt[idx] = n*NBK + bi;   // idx == bh*LL + n*SS + s
}

// ---------------- per-(b,h) 256-bucket histogram + exclusive scan ----------------
__global__ void k_hist(const int* __restrict__ bkt, int* __restrict__ boff) {
    __shared__ int hist[256];
    int bh = blockIdx.x;
    hist[threadIdx.x] = 0;
    __syncthreads();
    const int* p = bkt + (size_t)bh*LL;
    for (int i = threadIdx.x; i < LL; i += 256) atomicAdd(&hist[p[i]], 1);
    __syncthreads();
    if (threadIdx.x == 0) {
        int run = 0;
        for (int k = 0; k < 256; k++) { int c = hist[k]; boff[bh*256 + k] = run; run += c; }
    }
}

// ---------------- stable rank + scatter: one block per (b,h,round) ----------------
__global__ void k_scatter(const int* __restrict__ bkt, const int* __restrict__ boff,
                          int* __restrict__ sticker, int* __restrict__ undo) {
    __shared__ int hist[256*NBK];      // 32 KB
    int blk = blockIdx.x;              // B*H*NHASH
    int n = blk % NHASH, bh = blk / NHASH;
    int t = threadIdx.x;               // 256 threads, 8 consecutive elems each
    #pragma unroll
    for (int k = 0; k < NBK; k++) hist[t*NBK + k] = 0;
    const int* bp = bkt + (size_t)bh*LL + n*SS;
    int local[8];
    #pragma unroll
    for (int e = 0; e < 8; e++) {
        int k = bp[t*8 + e] - n*NBK;
        local[e] = k;
        hist[t*NBK + k]++;
    }
    __syncthreads();
    if (t < NBK) {
        int run = boff[bh*256 + n*NBK + t];
        for (int tt = 0; tt < 256; tt++) {
            int c = hist[tt*NBK + t];
            hist[tt*NBK + t] = run;
            run += c;
        }
    }
    __syncthreads();
    #pragma unroll
    for (int e = 0; e < 8; e++) {
        int k = local[e];
        int pos = hist[t*NBK + k]++;
        int l = n*SS + t*8 + e;
        sticker[(size_t)bh*LL + pos] = l;
        undo[(size_t)bh*LL + l] = pos;
    }
}

// ---------------- chunked look-back attention: one block (64 thr) per (b,h,chunk) ----------------
__global__ void k_attn(const float* __restrict__ qk, const float* __restrict__ v,
                       const int* __restrict__ sticker, float* __restrict__ so,
                       float* __restrict__ slog) {
    __shared__ float Ks[2*BUCKET][DH];
    __shared__ float Vs[2*BUCKET][DH];
    __shared__ int   pk[2*BUCKET];
    int blk = blockIdx.x;              // B*H*NCHUNK
    int c = blk % NCHUNK, bh = blk / NCHUNK;
    int j = threadIdx.x;               // 64
    const int* stk = sticker + (size_t)bh*LL;
    const float* qkb = qk + (size_t)bh*SS*DH;
    const float* vb  = v  + (size_t)bh*SS*DH;
    #pragma unroll
    for (int rr = 0; rr < 2; rr++) {
        int jj = j + rr*BUCKET;
        int cc = (rr == 0) ? c : (c + NCHUNK - 1) % NCHUNK;
        int sk = stk[cc*BUCKET + j] % SS;
        const float* kp = qkb + (size_t)sk*DH;
        float kv[DH]; float ssq = 0.f;
        #pragma unroll
        for (int d = 0; d < DH; d++) { kv[d] = kp[d]; ssq += kv[d]*kv[d]; }
        float inv = 1.0f / sqrtf(ssq);
        #pragma unroll
        for (int d = 0; d < DH; d++) Ks[jj][d] = kv[d]*inv;
        const float* vp = vb + (size_t)sk*DH;
        #pragma unroll
        for (int d = 0; d < DH; d++) Vs[jj][d] = vp[d];
        pk[jj] = sk;
    }
    __syncthreads();
    int i = c*BUCKET + j;
    int sq = stk[i] % SS;
    const float* qp = qkb + (size_t)sq*DH;
    float q[DH];
    #pragma unroll
    for (int d = 0; d < DH; d++) q[d] = qp[d];
    // pass 1: max
    float m = -3.4e38f;
    for (int jj = 0; jj < 2*BUCKET; jj++) {
        float acc = 0.f;
        #pragma unroll
        for (int d = 0; d < DH; d++) acc += q[d]*Ks[jj][d];
        acc *= 0.25f;
        if (sq == pk[jj]) acc = -5e4f;
        m = fmaxf(m, acc);
    }
    // pass 2: exp-sum + PV
    float sum = 0.f;
    float o[DH];
    #pragma unroll
    for (int d = 0; d < DH; d++) o[d] = 0.f;
    for (int jj = 0; jj < 2*BUCKET; jj++) {
        float acc = 0.f;
        #pragma unroll
        for (int d = 0; d < DH; d++) acc += q[d]*Ks[jj][d];
        acc *= 0.25f;
        if (sq == pk[jj]) acc = -5e4f;
        float p = expf(acc - m);
        sum += p;
        #pragma unroll
        for (int d = 0; d < DH; d++) o[d] += p*Vs[jj][d];
    }
    float invs = 1.0f / sum;
    float* op = so + ((size_t)bh*LL + i)*DH;
    #pragma unroll
    for (int d = 0; d < DH; d++) op[d] = o[d]*invs;
    slog[(size_t)bh*LL + i] = m + logf(sum);
}

// ---------------- unsort + softmax-combine over hash rounds ----------------
__global__ void k_combine(const float* __restrict__ so, const float* __restrict__ slog,
                          const int* __restrict__ undo, float* __restrict__ attn) {
    int idx = blockIdx.x * blockDim.x + threadIdx.x;  // B*H*S
    if (idx >= NBH*SS) return;
    int s = idx % SS, bh = idx / SS;
    int b = bh / HH, h_ = bh % HH;
    const int* up = undo + (size_t)bh*LL;
    const float* sl = slog + (size_t)bh*LL;
    float lg[NHASH]; int ps[NHASH];
    float m = -3.4e38f;
    #pragma unroll
    for (int n = 0; n < NHASH; n++) {
        int p = up[n*SS + s];
        ps[n] = p;
        lg[n] = sl[p];
        m = fmaxf(m, lg[n]);
    }
    float sum = 0.f;
    #pragma unroll
    for (int n = 0; n < NHASH; n++) { lg[n] = expf(lg[n] - m); sum += lg[n]; }
    float inv = 1.0f / sum;
    float o[DH];
    #pragma unroll
    for (int d = 0; d < DH; d++) o[d] = 0.f;
    #pragma unroll
    for (int n = 0; n < NHASH; n++) {
        float wgt = lg[n]*inv;
        const float* sp = so + ((size_t)bh*LL + ps[n])*DH;
        #pragma unroll
        for (int d = 0; d < DH; d++) o[d] += wgt*sp[d];
    }
    float* ap = attn + ((size_t)(b*SS + s))*DD + h_*DH;
    #pragma unroll
    for (int d = 0; d < DH; d++) ap[d] = o[d];
}

// ---------------- Wo projection + residual ----------------
__global__ void k_wo_res(const float* __restrict__ attn, const float* __restrict__ Wo,
                         float* __restrict__ h) {
    int idx = blockIdx.x * blockDim.x + threadIdx.x;  // B*S*D
    if (idx >= BB*SS*DD) return;
    int d = idx % DD, bs = idx / DD;
    const float* a = attn + (size_t)bs*DD;
    float acc = 0.f;
    #pragma unroll 4
    for (int k = 0; k < DD; k++) acc += a[k]*Wo[k*DD + d];
    h[idx] += acc;
}

// ---------------- FF1 with GELU (tanh approx) ----------------
__global__ void k_ff1(const float* __restrict__ y, const float* __restrict__ W1,
                      const float* __restrict__ b1, float* __restrict__ ff) {
    int idx = blockIdx.x * blockDim.x + threadIdx.x;  // B*S*DFF
    if (idx >= BB*SS*DFF) return;
    int f = idx % DFF, bs = idx / DFF;
    const float* a = y + (size_t)bs*DD;
    float acc = b1[f];
    #pragma unroll 4
    for (int k = 0; k < DD; k++) acc += a[k]*W1[k*DFF + f];
    float x = acc;
    float t = tanhf(0.7978845608028654f * (x + 0.044715f*x*x*x));
    ff[idx] = 0.5f*x*(1.0f + t);
}

// ---------------- FF2 + residual ----------------
__global__ void k_ff2_res(const float* __restrict__ ff, const float* __restrict__ W2,
                          const float* __restrict__ b2, float* __restrict__ h) {
    int idx = blockIdx.x * blockDim.x + threadIdx.x;  // B*S*D
    if (idx >= BB*SS*DD) return;
    int d = idx % DD, bs = idx / DD;
    const float* a = ff + (size_t)bs*DFF;
    float acc = b2[d];
    #pragma unroll 4
    for (int k = 0; k < DFF; k++) acc += a[k]*W2[k*DD + d];
    h[idx] += acc;
}

// ---------------- mean pool over sequence ----------------
__global__ void k_pool(const float* __restrict__ h, float* __restrict__ pooled) {
    int idx = blockIdx.x * blockDim.x + threadIdx.x;  // B*D
    if (idx >= BB*DD) return;
    int d = idx % DD, b = idx / DD;
    float acc = 0.f;
    for (int s = 0; s < SS; s++) acc += h[((size_t)(b*SS + s))*DD + d];
    pooled[idx] = acc * (1.0f/(float)SS);
}

// ---------------- final FC ----------------
__global__ void k_final(const float* __restrict__ pooled, const float* __restrict__ fcW,
                        const float* __restrict__ fcb, float* __restrict__ out) {
    int idx = threadIdx.x;   // 8 outputs
    if (idx >= BB*2) return;
    int c = idx % 2, b = idx / 2;
    float acc = fcb[c];
    #pragma unroll 4
    for (int d = 0; d < DD; d++) acc += pooled[b*DD + d]*fcW[d*2 + c];
    out[idx] = acc;
}

extern "C" void kernel_launch(void* const* d_in, const int* in_sizes, int n_in,
                              void* d_out, int out_size, void* d_ws, size_t ws_size,
                              hipStream_t stream) {
    const float* x    = (const float*)d_in[0];
    const float* embW = (const float*)d_in[1];
    const float* embB = (const float*)d_in[2];
    const float* Wqk  = (const float*)d_in[3];
    const float* Wv   = (const float*)d_in[4];
    const float* Wo   = (const float*)d_in[5];
    const float* R    = (const float*)d_in[6];
    const float* ln1g = (const float*)d_in[7];
    const float* ln1b = (const float*)d_in[8];
    const float* ln2g = (const float*)d_in[9];
    const float* ln2b = (const float*)d_in[10];
    const float* W1   = (const float*)d_in[11];
    const float* b1   = (const float*)d_in[12];
    const float* W2   = (const float*)d_in[13];
    const float* b2   = (const float*)d_in[14];
    const float* fcW  = (const float*)d_in[15];
    const float* fcb  = (const float*)d_in[16];
    float* out = (float*)d_out;

    char* w = (char*)d_ws;
    auto carve = [&](size_t bytes) -> char* {
        char* p = w;
        w += (bytes + 255) & ~(size_t)255;
        return p;
    };
    float* h       = (float*)carve((size_t)BB*SS*DD*4);       // 4 MB
    float* tmp     = (float*)carve((size_t)BB*SS*DD*4);       // 4 MB
    float* qk      = (float*)carve((size_t)NBH*SS*DH*4);      // 4 MB
    float* v       = (float*)carve((size_t)NBH*SS*DH*4);      // 4 MB
    int*   bkt     = (int*)  carve((size_t)NBH*LL*4);         // 2 MB
    int*   sticker = (int*)  carve((size_t)NBH*LL*4);         // 2 MB
    int*   undo    = (int*)  carve((size_t)NBH*LL*4);         // 2 MB
    int*   boff    = (int*)  carve((size_t)NBH*256*4);        // 32 KB
    float* so      = (float*)carve((size_t)NBH*LL*DH*4);      // 32 MB
    float* slog    = (float*)carve((size_t)NBH*LL*4);         // 2 MB
    float* attn    = (float*)carve((size_t)BB*SS*DD*4);       // 4 MB
    float* ff      = (float*)carve((size_t)BB*SS*DFF*4);      // 16 MB
    float* pooled  = (float*)carve((size_t)BB*DD*4);          // 2 KB

    k_embed<<<(BB*SS*DD)/256, 256, 0, stream>>>(x, embW, embB, h);

    for (int l = 0; l < DEPTH; l++) {
        const float* wqk = Wqk + (size_t)l*DD*DD;
        const float* wv  = Wv  + (size_t)l*DD*DD;
        const float* wo  = Wo  + (size_t)l*DD*DD;
        const float* rl  = R   + (size_t)l*HH*DH*NHASH*16;
        const float* g1  = ln1g + l*DD; const float* bg1 = ln1b + l*DD;
        const float* g2  = ln2g + l*DD; const float* bg2 = ln2b + l*DD;
        const float* w1  = W1 + (size_t)l*DD*DFF; const float* bb1 = b1 + l*DFF;
        const float* w2  = W2 + (size_t)l*DFF*DD; const float* bb2 = b2 + l*DD;

        k_layernorm<<<BB*SS, 64, 0, stream>>>(h, g1, bg1, tmp);
        k_proj_qkv<<<(BB*SS*DD)/256, 256, 0, stream>>>(tmp, wqk, wv, qk, v);
        k_hash<<<(NBH*NHASH*SS)/256, 256, 0, stream>>>(qk, rl, bkt);
        k_hist<<<NBH, 256, 0, stream>>>(bkt, boff);
        k_scatter<<<NBH*NHASH, 256, 0, stream>>>(bkt, boff, sticker, undo);
        k_attn<<<NBH*NCHUNK, 64, 0, stream>>>(qk, v, sticker, so, slog);
        k_combine<<<(NBH*SS)/256, 256, 0, stream>>>(so, slog, undo, attn);
        k_wo_res<<<(BB*SS*DD)/256, 256, 0, stream>>>(attn, wo, h);
        k_layernorm<<<BB*SS, 64, 0, stream>>>(h, g2, bg2, tmp);
        k_ff1<<<(BB*SS*DFF)/256, 256, 0, stream>>>(tmp, w1, bb1, ff);
        k_ff2_res<<<(BB*SS*DD)/256, 256, 0, stream>>>(ff, w2, bb2, h);
    }

    k_pool<<<(BB*DD + 255)/256, 256, 0, stream>>>(h, pooled);
    k_final<<<1, 64, 0, stream>>>(pooled, fcW, fcb, out);
}

// Round 2
// 1916.233 us; speedup vs baseline: 1.9655x; 1.9655x over previous
//
#include <hip/hip_runtime.h>
#include <math.h>

#define BB 4
#define SS 2048
#define INDIM 4
#define DD 128
#define HH 8
#define DH 16
#define DEPTH 6
#define BUCKET 64
#define NHASH 8
#define NBK 32                 // buckets per hash round
#define DFF 512
#define LL (NHASH*SS)          // 16384 per (b,h)
#define NCHUNK (NHASH*NBK)     // 256 chunks per (b,h)
#define NBH (BB*HH)            // 32

// ---------------- embedding: h = x @ embW + embb ----------------
__global__ void k_embed(const float* __restrict__ x, const float* __restrict__ W,
                        const float* __restrict__ b, float* __restrict__ h) {
    int idx = blockIdx.x * blockDim.x + threadIdx.x;   // B*S*D
    if (idx >= BB*SS*DD) return;
    int d = idx % DD, bs = idx / DD;
    const float* xr = x + bs*INDIM;
    float acc = b[d];
    #pragma unroll
    for (int k = 0; k < INDIM; k++) acc += xr[k] * W[k*DD + d];
    h[idx] = acc;
}

// ---------------- layernorm: one 64-thread wave per row ----------------
__global__ void k_layernorm(const float* __restrict__ in, const float* __restrict__ g,
                            const float* __restrict__ b, float* __restrict__ out) {
    int row = blockIdx.x;                 // B*S rows
    int t = threadIdx.x;                  // 64 threads
    const float2* xr = (const float2*)(in + (size_t)row*DD);
    float2 x = xr[t];
    float s = x.x + x.y;
    #pragma unroll
    for (int o = 32; o >= 1; o >>= 1) s += __shfl_xor(s, o);
    float m = s * (1.0f/128.0f);
    float d0 = x.x - m, d1 = x.y - m;
    float vs = d0*d0 + d1*d1;
    #pragma unroll
    for (int o = 32; o >= 1; o >>= 1) vs += __shfl_xor(vs, o);
    float inv = 1.0f / sqrtf(vs * (1.0f/128.0f) + 1e-5f);
    float2 gg = ((const float2*)g)[t];
    float2 bb = ((const float2*)b)[t];
    float2 r;
    r.x = d0*inv*gg.x + bb.x;
    r.y = d1*inv*gg.y + bb.y;
    ((float2*)(out + (size_t)row*DD))[t] = r;
}

// ---------------- qk & v projections: LDS-tiled, 16 rows/block ----------------
__global__ void k_proj_qkv(const float* __restrict__ ln, const float* __restrict__ Wqk,
                           const float* __restrict__ Wv, float* __restrict__ qk,
                           float* __restrict__ v) {
    __shared__ float A[16][128];
    int row0 = blockIdx.x * 16;
    int t = threadIdx.x;                  // 256
    {
        const float4* src = (const float4*)(ln + (size_t)row0*DD);
        float4* dst = (float4*)&A[0][0];
        dst[t]       = src[t];
        dst[t + 256] = src[t + 256];
    }
    __syncthreads();
    int n = t & 127, g = t >> 7;
    float accq[8], accv[8];
    #pragma unroll
    for (int r = 0; r < 8; r++) { accq[r] = 0.f; accv[r] = 0.f; }
    for (int k4 = 0; k4 < 32; k4++) {
        float wq0 = Wqk[(k4*4+0)*DD + n], wq1 = Wqk[(k4*4+1)*DD + n];
        float wq2 = Wqk[(k4*4+2)*DD + n], wq3 = Wqk[(k4*4+3)*DD + n];
        float wv0 = Wv [(k4*4+0)*DD + n], wv1 = Wv [(k4*4+1)*DD + n];
        float wv2 = Wv [(k4*4+2)*DD + n], wv3 = Wv [(k4*4+3)*DD + n];
        #pragma unroll
        for (int r = 0; r < 8; r++) {
            float4 a = *(const float4*)&A[g*8 + r][k4*4];
            accq[r] += a.x*wq0 + a.y*wq1 + a.z*wq2 + a.w*wq3;
            accv[r] += a.x*wv0 + a.y*wv1 + a.z*wv2 + a.w*wv3;
        }
    }
    int h_ = n >> 4, d_ = n & 15;
    int b = row0 / SS;                    // 16 | 2048, block never crosses batch
    #pragma unroll
    for (int r = 0; r < 8; r++) {
        int row = row0 + g*8 + r;
        int s = row & (SS-1);
        size_t o = (((size_t)(b*HH + h_))*SS + s)*DH + d_;
        qk[o] = accq[r]; v[o] = accv[r];
    }
}

// ---------------- LSH hashing + fused global histogram ----------------
__global__ void k_hash(const float* __restrict__ qk, const float* __restrict__ R,
                       int* __restrict__ bkt, int* __restrict__ hist) {
    __shared__ float Rs[256];             // R[h_][d][n][r] for block-uniform (h_,n)
    int idx = blockIdx.x*256 + threadIdx.x;   // [bh][n][s]
    int s = idx & (SS-1); int t2 = idx >> 11;
    int n = t2 & 7; int bh = t2 >> 3; int h_ = bh & 7;
    {
        int tt = threadIdx.x;
        int d = tt >> 4, r = tt & 15;
        Rs[tt] = R[(((h_*DH + d)*NHASH + n)*16) + r];
    }
    __syncthreads();
    const float4* q4 = (const float4*)(qk + ((size_t)bh*SS + s)*DH);
    float4 q0 = q4[0], q1 = q4[1], q2 = q4[2], q3 = q4[3];
    float rxv[16];
    #pragma unroll
    for (int r = 0; r < 16; r++) {
        rxv[r] = q0.x*Rs[  0+r] + q0.y*Rs[ 16+r] + q0.z*Rs[ 32+r] + q0.w*Rs[ 48+r]
               + q1.x*Rs[ 64+r] + q1.y*Rs[ 80+r] + q1.z*Rs[ 96+r] + q1.w*Rs[112+r]
               + q2.x*Rs[128+r] + q2.y*Rs[144+r] + q2.z*Rs[160+r] + q2.w*Rs[176+r]
               + q3.x*Rs[192+r] + q3.y*Rs[208+r] + q3.z*Rs[224+r] + q3.w*Rs[240+r];
    }
    float best = rxv[0]; int bi = 0;
    #pragma unroll
    for (int jx = 1; jx < 16; jx++) if (rxv[jx]  > best) { best = rxv[jx];  bi = jx; }
    #pragma unroll
    for (int jx = 0; jx < 16; jx++) if (-rxv[jx] > best) { best = -rxv[jx]; bi = 16 + jx; }
    int bucket = n*NBK + bi;
    bkt[idx] = bucket;
    atomicAdd(&hist[bh*256 + bucket], 1);
}

__global__ void k_zero(int* __restrict__ p) {
    p[blockIdx.x*256 + threadIdx.x] = 0;
}

// exclusive scan of 256 bucket counts per (b,h)
__global__ void k_scan(const int* __restrict__ hist, int* __restrict__ boff) {
    __shared__ int tmp[256];
    int bh = blockIdx.x, t = threadIdx.x;
    int x = hist[bh*256 + t];
    tmp[t] = x;
    __syncthreads();
    for (int o = 1; o < 256; o <<= 1) {
        int y = (t >= o) ? tmp[t-o] : 0;
        __syncthreads();
        tmp[t] += y;
        __syncthreads();
    }
    boff[bh*256 + t] = tmp[t] - x;
}

// ---------------- stable rank + scatter: one block per (b,h,round) ----------------
__global__ void k_scatter(const int* __restrict__ bkt, const int* __restrict__ boff,
                          int* __restrict__ sticker, int* __restrict__ undo) {
    __shared__ int hist[256*NBK];      // 32 KB
    int blk = blockIdx.x;              // B*H*NHASH
    int n = blk % NHASH, bh = blk / NHASH;
    int t = threadIdx.x;               // 256 threads, 8 consecutive elems each
    #pragma unroll
    for (int k = 0; k < NBK; k++) hist[t*NBK + k] = 0;
    const int* bp = bkt + (size_t)bh*LL + n*SS;
    int local[8];
    #pragma unroll
    for (int e = 0; e < 8; e++) {
        int k = bp[t*8 + e] - n*NBK;
        local[e] = k;
        hist[t*NBK + k]++;
    }
    __syncthreads();
    if (t < NBK) {
        int run = boff[bh*256 + n*NBK + t];
        for (int tt = 0; tt < 256; tt++) {
            int c = hist[tt*NBK + t];
            hist[tt*NBK + t] = run;
            run += c;
        }
    }
    __syncthreads();
    #pragma unroll
    for (int e = 0; e < 8; e++) {
        int k = local[e];
        int pos = hist[t*NBK + k]++;
        int l = n*SS + t*8 + e;
        sticker[(size_t)bh*LL + pos] = l;
        undo[(size_t)bh*LL + l] = pos;
    }
}

// ---------------- chunked look-back attention ----------------
// single pass (fixed max = 0 is safe: |dot| <= 0.25*|q| ~ 1), transposed
// conflict-free LDS, float4 b128 traffic throughout.
__global__ void k_attn(const float* __restrict__ qk, const float* __restrict__ v,
                       const int* __restrict__ sticker, float* __restrict__ so,
                       float* __restrict__ slog) {
    __shared__ float4 KsT[4][2*BUCKET];
    __shared__ float4 VsT[4][2*BUCKET];
    __shared__ int    pk[2*BUCKET];
    int blk = blockIdx.x;              // B*H*NCHUNK
    int c = blk & (NCHUNK-1), bh = blk >> 8;
    int j = threadIdx.x;               // 64
    const int* stk = sticker + (size_t)bh*LL;
    const float4* qkb = (const float4*)(qk + (size_t)bh*SS*DH);
    const float4* vb  = (const float4*)(v  + (size_t)bh*SS*DH);
    int sq = 0;
    float4 q0, q1, q2, q3;
    #pragma unroll
    for (int rr = 0; rr < 2; rr++) {
        int jj = j + rr*BUCKET;
        int cc = rr ? ((c + NCHUNK - 1) & (NCHUNK-1)) : c;
        int sk = stk[cc*BUCKET + j] & (SS-1);
        float4 k0 = qkb[sk*4+0], k1 = qkb[sk*4+1], k2 = qkb[sk*4+2], k3 = qkb[sk*4+3];
        if (rr == 0) { sq = sk; q0 = k0; q1 = k1; q2 = k2; q3 = k3; }
        float ssq = k0.x*k0.x + k0.y*k0.y + k0.z*k0.z + k0.w*k0.w
                  + k1.x*k1.x + k1.y*k1.y + k1.z*k1.z + k1.w*k1.w
                  + k2.x*k2.x + k2.y*k2.y + k2.z*k2.z + k2.w*k2.w
                  + k3.x*k3.x + k3.y*k3.y + k3.z*k3.z + k3.w*k3.w;
        float inv = 1.0f / sqrtf(ssq);
        k0.x *= inv; k0.y *= inv; k0.z *= inv; k0.w *= inv;
        k1.x *= inv; k1.y *= inv; k1.z *= inv; k1.w *= inv;
        k2.x *= inv; k2.y *= inv; k2.z *= inv; k2.w *= inv;
        k3.x *= inv; k3.y *= inv; k3.z *= inv; k3.w *= inv;
        KsT[0][jj] = k0; KsT[1][jj] = k1; KsT[2][jj] = k2; KsT[3][jj] = k3;
        VsT[0][jj] = vb[sk*4+0]; VsT[1][jj] = vb[sk*4+1];
        VsT[2][jj] = vb[sk*4+2]; VsT[3][jj] = vb[sk*4+3];
        pk[jj] = sk;
    }
    __syncthreads();
    const float sc = 0.25f;
    q0.x *= sc; q0.y *= sc; q0.z *= sc; q0.w *= sc;
    q1.x *= sc; q1.y *= sc; q1.z *= sc; q1.w *= sc;
    q2.x *= sc; q2.y *= sc; q2.z *= sc; q2.w *= sc;
    q3.x *= sc; q3.y *= sc; q3.z *= sc; q3.w *= sc;
    float sum = 0.f;
    float4 o0 = {0,0,0,0}, o1 = {0,0,0,0}, o2 = {0,0,0,0}, o3 = {0,0,0,0};
    for (int jj = 0; jj < 2*BUCKET; jj++) {
        float4 ka = KsT[0][jj], kb = KsT[1][jj], kc = KsT[2][jj], kd = KsT[3][jj];
        float d0 = q0.x*ka.x + q0.y*ka.y + q0.z*ka.z + q0.w*ka.w;
        float d1 = q1.x*kb.x + q1.y*kb.y + q1.z*kb.z + q1.w*kb.w;
        float d2 = q2.x*kc.x + q2.y*kc.y + q2.z*kc.z + q2.w*kc.w;
        float d3 = q3.x*kd.x + q3.y*kd.y + q3.z*kd.z + q3.w*kd.w;
        float acc = (d0 + d1) + (d2 + d3);
        acc = (sq == pk[jj]) ? -5e4f : acc;
        float p = __expf(acc);
        sum += p;
        float4 va = VsT[0][jj], vb4 = VsT[1][jj], vc = VsT[2][jj], vd = VsT[3][jj];
        o0.x += p*va.x;  o0.y += p*va.y;  o0.z += p*va.z;  o0.w += p*va.w;
        o1.x += p*vb4.x; o1.y += p*vb4.y; o1.z += p*vb4.z; o1.w += p*vb4.w;
        o2.x += p*vc.x;  o2.y += p*vc.y;  o2.z += p*vc.z;  o2.w += p*vc.w;
        o3.x += p*vd.x;  o3.y += p*vd.y;  o3.z += p*vd.z;  o3.w += p*vd.w;
    }
    int i = c*BUCKET + j;
    float invs = 1.0f / sum;
    o0.x *= invs; o0.y *= invs; o0.z *= invs; o0.w *= invs;
    o1.x *= invs; o1.y *= invs; o1.z *= invs; o1.w *= invs;
    o2.x *= invs; o2.y *= invs; o2.z *= invs; o2.w *= invs;
    o3.x *= invs; o3.y *= invs; o3.z *= invs; o3.w *= invs;
    float4* op = (float4*)(so + (((size_t)bh*LL + i)*DH));
    op[0] = o0; op[1] = o1; op[2] = o2; op[3] = o3;
    slog[(size_t)bh*LL + i] = __logf(sum);
}

// ---------------- unsort + softmax-combine over hash rounds ----------------
__global__ void k_combine(const float* __restrict__ so, const float* __restrict__ slog,
                          const int* __restrict__ undo, float* __restrict__ attn) {
    int idx = blockIdx.x * blockDim.x + threadIdx.x;  // B*H*S
    if (idx >= NBH*SS) return;
    int s = idx & (SS-1), bh = idx >> 11;
    int b = bh / HH, h_ = bh % HH;
    const int* up = undo + (size_t)bh*LL;
    const float* sl = slog + (size_t)bh*LL;
    float lg[NHASH]; int ps[NHASH];
    float m = -3.4e38f;
    #pragma unroll
    for (int n = 0; n < NHASH; n++) {
        int p = up[n*SS + s];
        ps[n] = p;
        lg[n] = sl[p];
        m = fmaxf(m, lg[n]);
    }
    float sum = 0.f;
    #pragma unroll
    for (int n = 0; n < NHASH; n++) { lg[n] = __expf(lg[n] - m); sum += lg[n]; }
    float inv = 1.0f / sum;
    float4 o0 = {0,0,0,0}, o1 = {0,0,0,0}, o2 = {0,0,0,0}, o3 = {0,0,0,0};
    const float4* so4 = (const float4*)so;
    #pragma unroll
    for (int n = 0; n < NHASH; n++) {
        float wgt = lg[n]*inv;
        const float4* sp = so4 + ((size_t)bh*LL + ps[n])*4;
        float4 a = sp[0], bq = sp[1], cq = sp[2], dq = sp[3];
        o0.x += wgt*a.x;  o0.y += wgt*a.y;  o0.z += wgt*a.z;  o0.w += wgt*a.w;
        o1.x += wgt*bq.x; o1.y += wgt*bq.y; o1.z += wgt*bq.z; o1.w += wgt*bq.w;
        o2.x += wgt*cq.x; o2.y += wgt*cq.y; o2.z += wgt*cq.z; o2.w += wgt*cq.w;
        o3.x += wgt*dq.x; o3.y += wgt*dq.y; o3.z += wgt*dq.z; o3.w += wgt*dq.w;
    }
    float4* ap = (float4*)(attn + ((size_t)(b*SS + s))*DD + h_*DH);
    ap[0] = o0; ap[1] = o1; ap[2] = o2; ap[3] = o3;
}

// ---------------- Wo projection + residual: LDS-tiled ----------------
__global__ void k_wo_res(const float* __restrict__ attn, const float* __restrict__ Wo,
                         float* __restrict__ h) {
    __shared__ float A[16][128];
    int row0 = blockIdx.x * 16;
    int t = threadIdx.x;
    {
        const float4* src = (const float4*)(attn + (size_t)row0*DD);
        float4* dst = (float4*)&A[0][0];
        dst[t]       = src[t];
        dst[t + 256] = src[t + 256];
    }
    __syncthreads();
    int n = t & 127, g = t >> 7;
    float acc[8];
    #pragma unroll
    for (int r = 0; r < 8; r++) acc[r] = 0.f;
    for (int k4 = 0; k4 < 32; k4++) {
        float w0 = Wo[(k4*4+0)*DD + n], w1 = Wo[(k4*4+1)*DD + n];
        float w2 = Wo[(k4*4+2)*DD + n], w3 = Wo[(k4*4+3)*DD + n];
        #pragma unroll
        for (int r = 0; r < 8; r++) {
            float4 a = *(const float4*)&A[g*8 + r][k4*4];
            acc[r] += a.x*w0 + a.y*w1 + a.z*w2 + a.w*w3;
        }
    }
    #pragma unroll
    for (int r = 0; r < 8; r++)
        h[(size_t)(row0 + g*8 + r)*DD + n] += acc[r];
}

// ---------------- FF1 with GELU: LDS-tiled, 8 rows/block ----------------
__global__ void k_ff1(const float* __restrict__ y, const float* __restrict__ W1,
                      const float* __restrict__ b1, float* __restrict__ ff) {
    __shared__ float A[8][128];
    int row0 = blockIdx.x * 8;
    int t = threadIdx.x;
    {
        const float4* src = (const float4*)(y + (size_t)row0*DD);
        float4* dst = (float4*)&A[0][0];
        dst[t] = src[t];
    }
    __syncthreads();
    int c0 = t, c1 = t + 256;
    float acc0[8], acc1[8];
    float bias0 = b1[c0], bias1 = b1[c1];
    #pragma unroll
    for (int r = 0; r < 8; r++) { acc0[r] = bias0; acc1[r] = bias1; }
    for (int k4 = 0; k4 < 32; k4++) {
        float wa0 = W1[(k4*4+0)*DFF + c0], wa1 = W1[(k4*4+1)*DFF + c0];
        float wa2 = W1[(k4*4+2)*DFF + c0], wa3 = W1[(k4*4+3)*DFF + c0];
        float wb0 = W1[(k4*4+0)*DFF + c1], wb1 = W1[(k4*4+1)*DFF + c1];
        float wb2 = W1[(k4*4+2)*DFF + c1], wb3 = W1[(k4*4+3)*DFF + c1];
        #pragma unroll
        for (int r = 0; r < 8; r++) {
            float4 a = *(const float4*)&A[r][k4*4];
            acc0[r] += a.x*wa0 + a.y*wa1 + a.z*wa2 + a.w*wa3;
            acc1[r] += a.x*wb0 + a.y*wb1 + a.z*wb2 + a.w*wb3;
        }
    }
    #pragma unroll
    for (int r = 0; r < 8; r++) {
        float x0 = acc0[r];
        float t0 = tanhf(0.7978845608028654f * (x0 + 0.044715f*x0*x0*x0));
        ff[(size_t)(row0 + r)*DFF + c0] = 0.5f*x0*(1.0f + t0);
        float x1 = acc1[r];
        float t1 = tanhf(0.7978845608028654f * (x1 + 0.044715f*x1*x1*x1));
        ff[(size_t)(row0 + r)*DFF + c1] = 0.5f*x1*(1.0f + t1);
    }
}

// ---------------- FF2 + residual: LDS-tiled, 16 rows/block ----------------
__global__ void k_ff2_res(const float* __restrict__ ff, const float* __restrict__ W2,
                          const float* __restrict__ b2, float* __restrict__ h) {
    __shared__ float A[16][512];          // 32 KB
    int row0 = blockIdx.x * 16;
    int t = threadIdx.x;
    {
        const float4* src = (const float4*)(ff + (size_t)row0*DFF);
        float4* dst = (float4*)&A[0][0];
        #pragma unroll
        for (int i = 0; i < 8; i++) dst[t + i*256] = src[t + i*256];
    }
    __syncthreads();
    int col = t & 127, g = t >> 7;
    float acc[8];
    #pragma unroll
    for (int r = 0; r < 8; r++) acc[r] = 0.f;
    for (int k4 = 0; k4 < 128; k4++) {
        float w0 = W2[(k4*4+0)*DD + col], w1 = W2[(k4*4+1)*DD + col];
        float w2 = W2[(k4*4+2)*DD + col], w3 = W2[(k4*4+3)*DD + col];
        #pragma unroll
        for (int r = 0; r < 8; r++) {
            float4 a = *(const float4*)&A[g*8 + r][k4*4];
            acc[r] += a.x*w0 + a.y*w1 + a.z*w2 + a.w*w3;
        }
    }
    float bias = b2[col];
    #pragma unroll
    for (int r = 0; r < 8; r++)
        h[(size_t)(row0 + g*8 + r)*DD + col] += acc[r] + bias;
}

// ---------------- fused mean-pool + final FC: one block per batch ----------------
__global__ void k_final(const float* __restrict__ h, const float* __restrict__ fcW,
                        const float* __restrict__ fcb, float* __restrict__ out) {
    __shared__ float Wl[256];
    __shared__ float red[512];
    int b = blockIdx.x, t = threadIdx.x;   // 256 threads
    Wl[t] = fcW[t];
    __syncthreads();
    float a0 = 0.f, a1 = 0.f;
    for (int s = t; s < SS; s += 256) {
        const float4* hr = (const float4*)(h + ((size_t)(b*SS + s))*DD);
        #pragma unroll
        for (int d4 = 0; d4 < 32; d4++) {
            float4 hv = hr[d4];
            a0 += hv.x*Wl[(d4*4+0)*2+0] + hv.y*Wl[(d4*4+1)*2+0]
                + hv.z*Wl[(d4*4+2)*2+0] + hv.w*Wl[(d4*4+3)*2+0];
            a1 += hv.x*Wl[(d4*4+0)*2+1] + hv.y*Wl[(d4*4+1)*2+1]
                + hv.z*Wl[(d4*4+2)*2+1] + hv.w*Wl[(d4*4+3)*2+1];
        }
    }
    red[t] = a0; red[256 + t] = a1;
    __syncthreads();
    for (int o = 128; o >= 1; o >>= 1) {
        if (t < o) { red[t] += red[t + o]; red[256 + t] += red[256 + t + o]; }
        __syncthreads();
    }
    if (t == 0) {
        out[b*2 + 0] = red[0]  *(1.0f/(float)SS) + fcb[0];
        out[b*2 + 1] = red[256]*(1.0f/(float)SS) + fcb[1];
    }
}

extern "C" void kernel_launch(void* const* d_in, const int* in_sizes, int n_in,
                              void* d_out, int out_size, void* d_ws, size_t ws_size,
                              hipStream_t stream) {
    const float* x    = (const float*)d_in[0];
    const float* embW = (const float*)d_in[1];
    const float* embB = (const float*)d_in[2];
    const float* Wqk  = (const float*)d_in[3];
    const float* Wv   = (const float*)d_in[4];
    const float* Wo   = (const float*)d_in[5];
    const float* R    = (const float*)d_in[6];
    const float* ln1g = (const float*)d_in[7];
    const float* ln1b = (const float*)d_in[8];
    const float* ln2g = (const float*)d_in[9];
    const float* ln2b = (const float*)d_in[10];
    const float* W1   = (const float*)d_in[11];
    const float* b1   = (const float*)d_in[12];
    const float* W2   = (const float*)d_in[13];
    const float* b2   = (const float*)d_in[14];
    const float* fcW  = (const float*)d_in[15];
    const float* fcb  = (const float*)d_in[16];
    float* out = (float*)d_out;

    char* w = (char*)d_ws;
    auto carve = [&](size_t bytes) -> char* {
        char* p = w;
        w += (bytes + 255) & ~(size_t)255;
        return p;
    };
    float* h       = (float*)carve((size_t)BB*SS*DD*4);
    float* tmp     = (float*)carve((size_t)BB*SS*DD*4);
    float* qk      = (float*)carve((size_t)NBH*SS*DH*4);
    float* v       = (float*)carve((size_t)NBH*SS*DH*4);
    int*   bkt     = (int*)  carve((size_t)NBH*LL*4);
    int*   sticker = (int*)  carve((size_t)NBH*LL*4);
    int*   undo    = (int*)  carve((size_t)NBH*LL*4);
    int*   hist    = (int*)  carve((size_t)NBH*256*4);
    int*   boff    = (int*)  carve((size_t)NBH*256*4);
    float* so      = (float*)carve((size_t)NBH*LL*DH*4);
    float* slog    = (float*)carve((size_t)NBH*LL*4);
    float* attn    = (float*)carve((size_t)BB*SS*DD*4);
    float* ff      = (float*)carve((size_t)BB*SS*DFF*4);

    k_embed<<<(BB*SS*DD)/256, 256, 0, stream>>>(x, embW, embB, h);

    for (int l = 0; l < DEPTH; l++) {
        const float* wqk = Wqk + (size_t)l*DD*DD;
        const float* wv  = Wv  + (size_t)l*DD*DD;
        const float* wo  = Wo  + (size_t)l*DD*DD;
        const float* rl  = R   + (size_t)l*HH*DH*NHASH*16;
        const float* g1  = ln1g + l*DD; const float* bg1 = ln1b + l*DD;
        const float* g2  = ln2g + l*DD; const float* bg2 = ln2b + l*DD;
        const float* w1  = W1 + (size_t)l*DD*DFF; const float* bb1 = b1 + l*DFF;
        const float* w2  = W2 + (size_t)l*DFF*DD; const float* bb2 = b2 + l*DD;

        k_layernorm<<<BB*SS, 64, 0, stream>>>(h, g1, bg1, tmp);
        k_proj_qkv<<<(BB*SS)/16, 256, 0, stream>>>(tmp, wqk, wv, qk, v);
        k_zero<<<(NBH*256)/256, 256, 0, stream>>>(hist);
        k_hash<<<(NBH*NHASH*SS)/256, 256, 0, stream>>>(qk, rl, bkt, hist);
        k_scan<<<NBH, 256, 0, stream>>>(hist, boff);
        k_scatter<<<NBH*NHASH, 256, 0, stream>>>(bkt, boff, sticker, undo);
        k_attn<<<NBH*NCHUNK, 64, 0, stream>>>(qk, v, sticker, so, slog);
        k_combine<<<(NBH*SS)/256, 256, 0, stream>>>(so, slog, undo, attn);
        k_wo_res<<<(BB*SS)/16, 256, 0, stream>>>(attn, wo, h);
        k_layernorm<<<BB*SS, 64, 0, stream>>>(h, g2, bg2, tmp);
        k_ff1<<<(BB*SS)/8, 256, 0, stream>>>(tmp, w1, bb1, ff);
        k_ff2_res<<<(BB*SS)/16, 256, 0, stream>>>(ff, w2, bb2, h);
    }

    k_final<<<BB, 256, 0, stream>>>(h, fcW, fcb, out);
}

// Round 3
// 1489.440 us; speedup vs baseline: 2.5288x; 1.2865x over previous
//
#include <hip/hip_runtime.h>
#include <math.h>

#define BB 4
#define SS 2048
#define INDIM 4
#define DD 128
#define HH 8
#define DH 16
#define DEPTH 6
#define BUCKET 64
#define NHASH 8
#define NBK 32                 // buckets per hash round
#define DFF 512
#define LL (NHASH*SS)          // 16384 per (b,h)
#define NCHUNK (NHASH*NBK)     // 256 chunks per (b,h)
#define NBH (BB*HH)            // 32

// ---------------- embedding: h = x @ embW + embb ----------------
__global__ void k_embed(const float* __restrict__ x, const float* __restrict__ W,
                        const float* __restrict__ b, float* __restrict__ h) {
    int idx = blockIdx.x * blockDim.x + threadIdx.x;   // B*S*D
    if (idx >= BB*SS*DD) return;
    int d = idx % DD, bs = idx / DD;
    const float* xr = x + bs*INDIM;
    float acc = b[d];
    #pragma unroll
    for (int k = 0; k < INDIM; k++) acc += xr[k] * W[k*DD + d];
    h[idx] = acc;
}

// ---------------- fused LN1 + qk/v projections: 16 rows/block ----------------
__global__ void k_proj_qkv(const float* __restrict__ hin, const float* __restrict__ lng,
                           const float* __restrict__ lnb, const float* __restrict__ Wqk,
                           const float* __restrict__ Wv, float* __restrict__ qk,
                           float* __restrict__ v) {
    __shared__ float A[16][128];
    int row0 = blockIdx.x * 16;
    int t = threadIdx.x;                  // 256
    {
        const float4* src = (const float4*)(hin + (size_t)row0*DD);
        float4* dst = (float4*)&A[0][0];
        dst[t]       = src[t];
        dst[t + 256] = src[t + 256];
    }
    __syncthreads();
    // layernorm: 16 threads per row, 8 elems each
    {
        int r = t >> 4, sub = t & 15;
        float4 xa = *(const float4*)&A[r][sub*8];
        float4 xb = *(const float4*)&A[r][sub*8 + 4];
        float s = xa.x+xa.y+xa.z+xa.w + xb.x+xb.y+xb.z+xb.w;
        s += __shfl_xor(s,1); s += __shfl_xor(s,2);
        s += __shfl_xor(s,4); s += __shfl_xor(s,8);
        float m = s * (1.0f/128.0f);
        float d0=xa.x-m, d1=xa.y-m, d2=xa.z-m, d3=xa.w-m;
        float d4=xb.x-m, d5=xb.y-m, d6=xb.z-m, d7=xb.w-m;
        float vs = d0*d0+d1*d1+d2*d2+d3*d3+d4*d4+d5*d5+d6*d6+d7*d7;
        vs += __shfl_xor(vs,1); vs += __shfl_xor(vs,2);
        vs += __shfl_xor(vs,4); vs += __shfl_xor(vs,8);
        float inv = 1.0f / sqrtf(vs * (1.0f/128.0f) + 1e-5f);
        float4 ga = *(const float4*)&lng[sub*8], gb = *(const float4*)&lng[sub*8+4];
        float4 ba = *(const float4*)&lnb[sub*8], bb = *(const float4*)&lnb[sub*8+4];
        float4 ra, rb;
        ra.x = d0*inv*ga.x + ba.x; ra.y = d1*inv*ga.y + ba.y;
        ra.z = d2*inv*ga.z + ba.z; ra.w = d3*inv*ga.w + ba.w;
        rb.x = d4*inv*gb.x + bb.x; rb.y = d5*inv*gb.y + bb.y;
        rb.z = d6*inv*gb.z + bb.z; rb.w = d7*inv*gb.w + bb.w;
        *(float4*)&A[r][sub*8]     = ra;
        *(float4*)&A[r][sub*8 + 4] = rb;
    }
    __syncthreads();
    int n = t & 127, g = t >> 7;
    float accq[8], accv[8];
    #pragma unroll
    for (int r = 0; r < 8; r++) { accq[r] = 0.f; accv[r] = 0.f; }
    for (int k4 = 0; k4 < 32; k4++) {
        float wq0 = Wqk[(k4*4+0)*DD + n], wq1 = Wqk[(k4*4+1)*DD + n];
        float wq2 = Wqk[(k4*4+2)*DD + n], wq3 = Wqk[(k4*4+3)*DD + n];
        float wv0 = Wv [(k4*4+0)*DD + n], wv1 = Wv [(k4*4+1)*DD + n];
        float wv2 = Wv [(k4*4+2)*DD + n], wv3 = Wv [(k4*4+3)*DD + n];
        #pragma unroll
        for (int r = 0; r < 8; r++) {
            float4 a = *(const float4*)&A[g*8 + r][k4*4];
            accq[r] += a.x*wq0 + a.y*wq1 + a.z*wq2 + a.w*wq3;
            accv[r] += a.x*wv0 + a.y*wv1 + a.z*wv2 + a.w*wv3;
        }
    }
    int h_ = n >> 4, d_ = n & 15;
    int b = row0 / SS;
    #pragma unroll
    for (int r = 0; r < 8; r++) {
        int row = row0 + g*8 + r;
        int s = row & (SS-1);
        size_t o = (((size_t)(b*HH + h_))*SS + s)*DH + d_;
        qk[o] = accq[r]; v[o] = accv[r];
    }
}

// ---------------- LSH hashing ----------------
__global__ void k_hash(const float* __restrict__ qk, const float* __restrict__ R,
                       int* __restrict__ bkt) {
    __shared__ float Rs[256];             // R[h_][d][n][r] for block-uniform (h_,n)
    int idx = blockIdx.x*256 + threadIdx.x;   // [bh][n][s]
    int s = idx & (SS-1); int t2 = idx >> 11;
    int n = t2 & 7; int bh = t2 >> 3; int h_ = bh & 7;
    {
        int tt = threadIdx.x;
        int d = tt >> 4, r = tt & 15;
        Rs[tt] = R[(((h_*DH + d)*NHASH + n)*16) + r];
    }
    __syncthreads();
    const float4* q4 = (const float4*)(qk + ((size_t)bh*SS + s)*DH);
    float4 q0 = q4[0], q1 = q4[1], q2 = q4[2], q3 = q4[3];
    float rxv[16];
    #pragma unroll
    for (int r = 0; r < 16; r++) {
        rxv[r] = q0.x*Rs[  0+r] + q0.y*Rs[ 16+r] + q0.z*Rs[ 32+r] + q0.w*Rs[ 48+r]
               + q1.x*Rs[ 64+r] + q1.y*Rs[ 80+r] + q1.z*Rs[ 96+r] + q1.w*Rs[112+r]
               + q2.x*Rs[128+r] + q2.y*Rs[144+r] + q2.z*Rs[160+r] + q2.w*Rs[176+r]
               + q3.x*Rs[192+r] + q3.y*Rs[208+r] + q3.z*Rs[224+r] + q3.w*Rs[240+r];
    }
    float best = rxv[0]; int bi = 0;
    #pragma unroll
    for (int jx = 1; jx < 16; jx++) if (rxv[jx]  > best) { best = rxv[jx];  bi = jx; }
    #pragma unroll
    for (int jx = 0; jx < 16; jx++) if (-rxv[jx] > best) { best = -rxv[jx]; bi = 16 + jx; }
    bkt[idx] = n*NBK + bi;
}

// ---------------- counting sort per (b,h,round): fused hist+scan+scatter ----------------
// Sort key is (bucket, pos) with bucket's high bits = round, so round n owns
// positions [n*SS, (n+1)*SS) exactly -> per-round independent counting sort.
__global__ void k_scatter(const int* __restrict__ bkt, int* __restrict__ sticker) {
    __shared__ int hist[256*33];       // padded stride 33: conflict-free columns
    __shared__ int cs[8*33];
    __shared__ int bb[NBK];
    int blk = blockIdx.x;              // B*H*NHASH
    int n = blk & 7, bh = blk >> 3;
    int t = threadIdx.x;               // 256 threads, 8 consecutive elems each
    #pragma unroll
    for (int k = 0; k < NBK; k++) hist[t*33 + k] = 0;
    const int* bp = bkt + (size_t)bh*LL + n*SS;
    int local[8];
    #pragma unroll
    for (int e = 0; e < 8; e++) {
        int k = bp[t*8 + e] - n*NBK;
        local[e] = k;
        hist[t*33 + k]++;
    }
    __syncthreads();
    // column partial sums: 8 threads per bucket column
    {
        int i = t >> 5, k = t & 31;
        int ssum = 0;
        #pragma unroll
        for (int rr = 0; rr < 32; rr++) ssum += hist[(i*32+rr)*33 + k];
        cs[i*33 + k] = ssum;
    }
    __syncthreads();
    // bucket bases: lanes 0..31 do exclusive scan over 32 bucket totals
    if (t < 32) {
        int tot = 0;
        #pragma unroll
        for (int i = 0; i < 8; i++) tot += cs[i*33 + t];
        int x = tot;
        #pragma unroll
        for (int o = 1; o < 32; o <<= 1) {
            int y = __shfl(x, (t >= o) ? (t - o) : 0, 64);
            if (t >= o) x += y;
        }
        bb[t] = n*SS + x - tot;        // exclusive prefix + round base
    }
    __syncthreads();
    // rewrite per-thread-row offsets (8-way parallel per column)
    {
        int i = t >> 5, k = t & 31;
        int run = bb[k];
        for (int ii = 0; ii < i; ii++) run += cs[ii*33 + k];
        for (int rr = 0; rr < 32; rr++) {
            int idx = (i*32+rr)*33 + k;
            int c0 = hist[idx];
            hist[idx] = run;
            run += c0;
        }
    }
    __syncthreads();
    #pragma unroll
    for (int e = 0; e < 8; e++) {
        int k = local[e];
        int pos = hist[t*33 + k]++;
        sticker[(size_t)bh*LL + pos] = n*SS + t*8 + e;
    }
}

// ---------------- chunked look-back attention ----------------
// 256 threads per chunk: 4 waves split the 128 keys, partials combined via
// LDS that aliases the K/V staging region. Output written UNSORTED (scatter
// by sticker) so k_combine reads coalesced. Fixed max=0 (|dot|<=0.25|q|~1).
__global__ __launch_bounds__(256, 8)
void k_attn(const float* __restrict__ qk, const float* __restrict__ v,
            const int* __restrict__ sticker, float* __restrict__ so,
            float* __restrict__ slog) {
    __shared__ float4 B4[1088];        // 17408 B
    float4* KsT = B4;                  // [4][128]
    float4* VsT = B4 + 512;            // [4][128]
    int*    pk  = (int*)(B4 + 1024);   // [128]
    float*  nrm = (float*)(B4 + 1024) + 128;  // [128] (|k| * 0.25)
    float*  P   = (float*)B4;          // alias: [4][64][17] partials

    int blk = blockIdx.x;              // B*H*NCHUNK
    int c = blk & (NCHUNK-1), bh = blk >> 8;
    int t = threadIdx.x;
    const int* stk = sticker + (size_t)bh*LL;
    const float4* qkb = (const float4*)(qk + (size_t)bh*SS*DH);
    const float4* vb  = (const float4*)(v  + (size_t)bh*SS*DH);

    // stage: threads 0-127 -> K rows (normalized), 128-255 -> V rows
    {
        int jj = t & 127;
        int cc = (jj < 64) ? c : ((c + NCHUNK - 1) & (NCHUNK-1));
        int sk = stk[cc*BUCKET + (jj & 63)] & (SS-1);
        if (t < 128) {
            float4 k0 = qkb[sk*4+0], k1 = qkb[sk*4+1], k2 = qkb[sk*4+2], k3 = qkb[sk*4+3];
            float ssq = k0.x*k0.x + k0.y*k0.y + k0.z*k0.z + k0.w*k0.w
                      + k1.x*k1.x + k1.y*k1.y + k1.z*k1.z + k1.w*k1.w
                      + k2.x*k2.x + k2.y*k2.y + k2.z*k2.z + k2.w*k2.w
                      + k3.x*k3.x + k3.y*k3.y + k3.z*k3.z + k3.w*k3.w;
            float nn = sqrtf(ssq);
            float inv = 1.0f / nn;
            k0.x*=inv; k0.y*=inv; k0.z*=inv; k0.w*=inv;
            k1.x*=inv; k1.y*=inv; k1.z*=inv; k1.w*=inv;
            k2.x*=inv; k2.y*=inv; k2.z*=inv; k2.w*=inv;
            k3.x*=inv; k3.y*=inv; k3.z*=inv; k3.w*=inv;
            KsT[      jj] = k0; KsT[128 + jj] = k1;
            KsT[256 + jj] = k2; KsT[384 + jj] = k3;
            pk[jj] = sk;
            nrm[jj] = nn * 0.25f;
        } else {
            VsT[      jj] = vb[sk*4+0]; VsT[128 + jj] = vb[sk*4+1];
            VsT[256 + jj] = vb[sk*4+2]; VsT[384 + jj] = vb[sk*4+3];
        }
    }
    __syncthreads();
    int w = t >> 6, j = t & 63;
    float scl = nrm[j];
    int sq = pk[j];
    float4 q0 = KsT[j], q1 = KsT[128+j], q2 = KsT[256+j], q3 = KsT[384+j];
    q0.x*=scl; q0.y*=scl; q0.z*=scl; q0.w*=scl;
    q1.x*=scl; q1.y*=scl; q1.z*=scl; q1.w*=scl;
    q2.x*=scl; q2.y*=scl; q2.z*=scl; q2.w*=scl;
    q3.x*=scl; q3.y*=scl; q3.z*=scl; q3.w*=scl;
    float psum = 0.f;
    float4 o0 = {0,0,0,0}, o1 = {0,0,0,0}, o2 = {0,0,0,0}, o3 = {0,0,0,0};
    int base = w*32;
    for (int r = 0; r < 32; r++) {
        int jj = base + r;
        float4 ka = KsT[jj], kb = KsT[128+jj], kc = KsT[256+jj], kd = KsT[384+jj];
        float d0 = q0.x*ka.x + q0.y*ka.y + q0.z*ka.z + q0.w*ka.w;
        float d1 = q1.x*kb.x + q1.y*kb.y + q1.z*kb.z + q1.w*kb.w;
        float d2 = q2.x*kc.x + q2.y*kc.y + q2.z*kc.z + q2.w*kc.w;
        float d3 = q3.x*kd.x + q3.y*kd.y + q3.z*kd.z + q3.w*kd.w;
        float acc = (d0 + d1) + (d2 + d3);
        acc = (sq == pk[jj]) ? -5e4f : acc;
        float p = __expf(acc);
        psum += p;
        float4 va = VsT[jj], vbb = VsT[128+jj], vc = VsT[256+jj], vd = VsT[384+jj];
        o0.x += p*va.x;  o0.y += p*va.y;  o0.z += p*va.z;  o0.w += p*va.w;
        o1.x += p*vbb.x; o1.y += p*vbb.y; o1.z += p*vbb.z; o1.w += p*vbb.w;
        o2.x += p*vc.x;  o2.y += p*vc.y;  o2.z += p*vc.z;  o2.w += p*vc.w;
        o3.x += p*vd.x;  o3.y += p*vd.y;  o3.z += p*vd.z;  o3.w += p*vd.w;
    }
    __syncthreads();   // everyone done reading K/V -> safe to overwrite with P
    {
        int pb = (w*64 + j)*17;
        P[pb+ 0]=o0.x; P[pb+ 1]=o0.y; P[pb+ 2]=o0.z; P[pb+ 3]=o0.w;
        P[pb+ 4]=o1.x; P[pb+ 5]=o1.y; P[pb+ 6]=o1.z; P[pb+ 7]=o1.w;
        P[pb+ 8]=o2.x; P[pb+ 9]=o2.y; P[pb+10]=o2.z; P[pb+11]=o2.w;
        P[pb+12]=o3.x; P[pb+13]=o3.y; P[pb+14]=o3.z; P[pb+15]=o3.w;
        P[pb+16]=psum;
    }
    __syncthreads();
    // finalize: thread (q = t&63, d4 = t>>6) sums 4 wave-partials
    {
        int q = t & 63, d4 = t >> 6;
        float s0 = P[q*17+16] + P[(64+q)*17+16] + P[(128+q)*17+16] + P[(192+q)*17+16];
        float inv = 1.0f / s0;
        int e = d4*4;
        float4 r;
        r.x = (P[q*17+e  ] + P[(64+q)*17+e  ] + P[(128+q)*17+e  ] + P[(192+q)*17+e  ]) * inv;
        r.y = (P[q*17+e+1] + P[(64+q)*17+e+1] + P[(128+q)*17+e+1] + P[(192+q)*17+e+1]) * inv;
        r.z = (P[q*17+e+2] + P[(64+q)*17+e+2] + P[(128+q)*17+e+2] + P[(192+q)*17+e+2]) * inv;
        r.w = (P[q*17+e+3] + P[(64+q)*17+e+3] + P[(128+q)*17+e+3] + P[(192+q)*17+e+3]) * inv;
        int l = stk[c*BUCKET + q];                 // unsorted (original) index
        ((float4*)(so + ((size_t)bh*LL + l)*DH))[d4] = r;
        if (d4 == 0) slog[(size_t)bh*LL + l] = __logf(s0);
    }
}

// ---------------- softmax-combine over hash rounds (coalesced reads) ----------------
__global__ void k_combine(const float* __restrict__ so, const float* __restrict__ slog,
                          float* __restrict__ attn) {
    int idx = blockIdx.x * blockDim.x + threadIdx.x;  // B*H*S
    if (idx >= NBH*SS) return;
    int s = idx & (SS-1), bh = idx >> 11;
    int b = bh >> 3, h_ = bh & 7;
    const float* sl = slog + (size_t)bh*LL;
    float lg[NHASH];
    float m = -3.4e38f;
    #pragma unroll
    for (int n = 0; n < NHASH; n++) {
        lg[n] = sl[n*SS + s];
        m = fmaxf(m, lg[n]);
    }
    float sum = 0.f;
    #pragma unroll
    for (int n = 0; n < NHASH; n++) { lg[n] = __expf(lg[n] - m); sum += lg[n]; }
    float inv = 1.0f / sum;
    float4 o0 = {0,0,0,0}, o1 = {0,0,0,0}, o2 = {0,0,0,0}, o3 = {0,0,0,0};
    #pragma unroll
    for (int n = 0; n < NHASH; n++) {
        float wgt = lg[n]*inv;
        const float4* sp = (const float4*)(so + ((size_t)bh*LL + n*SS + s)*DH);
        float4 a = sp[0], bq = sp[1], cq = sp[2], dq = sp[3];
        o0.x += wgt*a.x;  o0.y += wgt*a.y;  o0.z += wgt*a.z;  o0.w += wgt*a.w;
        o1.x += wgt*bq.x; o1.y += wgt*bq.y; o1.z += wgt*bq.z; o1.w += wgt*bq.w;
        o2.x += wgt*cq.x; o2.y += wgt*cq.y; o2.z += wgt*cq.z; o2.w += wgt*cq.w;
        o3.x += wgt*dq.x; o3.y += wgt*dq.y; o3.z += wgt*dq.z; o3.w += wgt*dq.w;
    }
    float4* ap = (float4*)(attn + ((size_t)(b*SS + s))*DD + h_*DH);
    ap[0] = o0; ap[1] = o1; ap[2] = o2; ap[3] = o3;
}

// ---------------- Wo projection + residual: LDS-tiled ----------------
__global__ void k_wo_res(const float* __restrict__ attn, const float* __restrict__ Wo,
                         float* __restrict__ h) {
    __shared__ float A[16][128];
    int row0 = blockIdx.x * 16;
    int t = threadIdx.x;
    {
        const float4* src = (const float4*)(attn + (size_t)row0*DD);
        float4* dst = (float4*)&A[0][0];
        dst[t]       = src[t];
        dst[t + 256] = src[t + 256];
    }
    __syncthreads();
    int n = t & 127, g = t >> 7;
    float acc[8];
    #pragma unroll
    for (int r = 0; r < 8; r++) acc[r] = 0.f;
    for (int k4 = 0; k4 < 32; k4++) {
        float w0 = Wo[(k4*4+0)*DD + n], w1 = Wo[(k4*4+1)*DD + n];
        float w2 = Wo[(k4*4+2)*DD + n], w3 = Wo[(k4*4+3)*DD + n];
        #pragma unroll
        for (int r = 0; r < 8; r++) {
            float4 a = *(const float4*)&A[g*8 + r][k4*4];
            acc[r] += a.x*w0 + a.y*w1 + a.z*w2 + a.w*w3;
        }
    }
    #pragma unroll
    for (int r = 0; r < 8; r++)
        h[(size_t)(row0 + g*8 + r)*DD + n] += acc[r];
}

// ---------------- fused LN2 + FF1 with GELU: 8 rows/block ----------------
__global__ void k_ff1(const float* __restrict__ hin, const float* __restrict__ lng,
                      const float* __restrict__ lnb, const float* __restrict__ W1,
                      const float* __restrict__ b1, float* __restrict__ ff) {
    __shared__ float A[8][128];
    int row0 = blockIdx.x * 8;
    int t = threadIdx.x;
    {
        const float4* src = (const float4*)(hin + (size_t)row0*DD);
        float4* dst = (float4*)&A[0][0];
        dst[t] = src[t];
    }
    __syncthreads();
    // layernorm: 32 threads per row, 4 elems each
    {
        int r = t >> 5, sub = t & 31;
        float4 x = *(const float4*)&A[r][sub*4];
        float s = x.x + x.y + x.z + x.w;
        s += __shfl_xor(s,1); s += __shfl_xor(s,2); s += __shfl_xor(s,4);
        s += __shfl_xor(s,8); s += __shfl_xor(s,16);
        float m = s * (1.0f/128.0f);
        float d0=x.x-m, d1=x.y-m, d2=x.z-m, d3=x.w-m;
        float vs = d0*d0 + d1*d1 + d2*d2 + d3*d3;
        vs += __shfl_xor(vs,1); vs += __shfl_xor(vs,2); vs += __shfl_xor(vs,4);
        vs += __shfl_xor(vs,8); vs += __shfl_xor(vs,16);
        float inv = 1.0f / sqrtf(vs * (1.0f/128.0f) + 1e-5f);
        float4 gg = *(const float4*)&lng[sub*4];
        float4 bb = *(const float4*)&lnb[sub*4];
        float4 r4;
        r4.x = d0*inv*gg.x + bb.x; r4.y = d1*inv*gg.y + bb.y;
        r4.z = d2*inv*gg.z + bb.z; r4.w = d3*inv*gg.w + bb.w;
        *(float4*)&A[r][sub*4] = r4;
    }
    __syncthreads();
    int c0 = t, c1 = t + 256;
    float acc0[8], acc1[8];
    float bias0 = b1[c0], bias1 = b1[c1];
    #pragma unroll
    for (int r = 0; r < 8; r++) { acc0[r] = bias0; acc1[r] = bias1; }
    for (int k4 = 0; k4 < 32; k4++) {
        float wa0 = W1[(k4*4+0)*DFF + c0], wa1 = W1[(k4*4+1)*DFF + c0];
        float wa2 = W1[(k4*4+2)*DFF + c0], wa3 = W1[(k4*4+3)*DFF + c0];
        float wb0 = W1[(k4*4+0)*DFF + c1], wb1 = W1[(k4*4+1)*DFF + c1];
        float wb2 = W1[(k4*4+2)*DFF + c1], wb3 = W1[(k4*4+3)*DFF + c1];
        #pragma unroll
        for (int r = 0; r < 8; r++) {
            float4 a = *(const float4*)&A[r][k4*4];
            acc0[r] += a.x*wa0 + a.y*wa1 + a.z*wa2 + a.w*wa3;
            acc1[r] += a.x*wb0 + a.y*wb1 + a.z*wb2 + a.w*wb3;
        }
    }
    #pragma unroll
    for (int r = 0; r < 8; r++) {
        float x0 = acc0[r];
        float t0 = tanhf(0.7978845608028654f * (x0 + 0.044715f*x0*x0*x0));
        ff[(size_t)(row0 + r)*DFF + c0] = 0.5f*x0*(1.0f + t0);
        float x1 = acc1[r];
        float t1 = tanhf(0.7978845608028654f * (x1 + 0.044715f*x1*x1*x1));
        ff[(size_t)(row0 + r)*DFF + c1] = 0.5f*x1*(1.0f + t1);
    }
}

// ---------------- FF2 + residual: LDS-tiled, 16 rows/block ----------------
__global__ void k_ff2_res(const float* __restrict__ ff, const float* __restrict__ W2,
                          const float* __restrict__ b2, float* __restrict__ h) {
    __shared__ float A[16][512];          // 32 KB
    int row0 = blockIdx.x * 16;
    int t = threadIdx.x;
    {
        const float4* src = (const float4*)(ff + (size_t)row0*DFF);
        float4* dst = (float4*)&A[0][0];
        #pragma unroll
        for (int i = 0; i < 8; i++) dst[t + i*256] = src[t + i*256];
    }
    __syncthreads();
    int col = t & 127, g = t >> 7;
    float acc[8];
    #pragma unroll
    for (int r = 0; r < 8; r++) acc[r] = 0.f;
    for (int k4 = 0; k4 < 128; k4++) {
        float w0 = W2[(k4*4+0)*DD + col], w1 = W2[(k4*4+1)*DD + col];
        float w2 = W2[(k4*4+2)*DD + col], w3 = W2[(k4*4+3)*DD + col];
        #pragma unroll
        for (int r = 0; r < 8; r++) {
            float4 a = *(const float4*)&A[g*8 + r][k4*4];
            acc[r] += a.x*w0 + a.y*w1 + a.z*w2 + a.w*w3;
        }
    }
    float bias = b2[col];
    #pragma unroll
    for (int r = 0; r < 8; r++)
        h[(size_t)(row0 + g*8 + r)*DD + col] += acc[r] + bias;
}

// ---------------- fused mean-pool + final FC: one block per batch ----------------
__global__ void k_final(const float* __restrict__ h, const float* __restrict__ fcW,
                        const float* __restrict__ fcb, float* __restrict__ out) {
    __shared__ float Wl[256];
    __shared__ float red[512];
    int b = blockIdx.x, t = threadIdx.x;   // 256 threads
    Wl[t] = fcW[t];
    __syncthreads();
    float a0 = 0.f, a1 = 0.f;
    for (int s = t; s < SS; s += 256) {
        const float4* hr = (const float4*)(h + ((size_t)(b*SS + s))*DD);
        #pragma unroll
        for (int d4 = 0; d4 < 32; d4++) {
            float4 hv = hr[d4];
            a0 += hv.x*Wl[(d4*4+0)*2+0] + hv.y*Wl[(d4*4+1)*2+0]
                + hv.z*Wl[(d4*4+2)*2+0] + hv.w*Wl[(d4*4+3)*2+0];
            a1 += hv.x*Wl[(d4*4+0)*2+1] + hv.y*Wl[(d4*4+1)*2+1]
                + hv.z*Wl[(d4*4+2)*2+1] + hv.w*Wl[(d4*4+3)*2+1];
        }
    }
    red[t] = a0; red[256 + t] = a1;
    __syncthreads();
    for (int o = 128; o >= 1; o >>= 1) {
        if (t < o) { red[t] += red[t + o]; red[256 + t] += red[256 + t + o]; }
        __syncthreads();
    }
    if (t == 0) {
        out[b*2 + 0] = red[0]  *(1.0f/(float)SS) + fcb[0];
        out[b*2 + 1] = red[256]*(1.0f/(float)SS) + fcb[1];
    }
}

extern "C" void kernel_launch(void* const* d_in, const int* in_sizes, int n_in,
                              void* d_out, int out_size, void* d_ws, size_t ws_size,
                              hipStream_t stream) {
    const float* x    = (const float*)d_in[0];
    const float* embW = (const float*)d_in[1];
    const float* embB = (const float*)d_in[2];
    const float* Wqk  = (const float*)d_in[3];
    const float* Wv   = (const float*)d_in[4];
    const float* Wo   = (const float*)d_in[5];
    const float* R    = (const float*)d_in[6];
    const float* ln1g = (const float*)d_in[7];
    const float* ln1b = (const float*)d_in[8];
    const float* ln2g = (const float*)d_in[9];
    const float* ln2b = (const float*)d_in[10];
    const float* W1   = (const float*)d_in[11];
    const float* b1   = (const float*)d_in[12];
    const float* W2   = (const float*)d_in[13];
    const float* b2   = (const float*)d_in[14];
    const float* fcW  = (const float*)d_in[15];
    const float* fcb  = (const float*)d_in[16];
    float* out = (float*)d_out;

    char* w = (char*)d_ws;
    auto carve = [&](size_t bytes) -> char* {
        char* p = w;
        w += (bytes + 255) & ~(size_t)255;
        return p;
    };
    float* h       = (float*)carve((size_t)BB*SS*DD*4);
    float* qk      = (float*)carve((size_t)NBH*SS*DH*4);
    float* v       = (float*)carve((size_t)NBH*SS*DH*4);
    int*   bkt     = (int*)  carve((size_t)NBH*LL*4);
    int*   sticker = (int*)  carve((size_t)NBH*LL*4);
    float* so      = (float*)carve((size_t)NBH*LL*DH*4);
    float* slog    = (float*)carve((size_t)NBH*LL*4);
    float* attn    = (float*)carve((size_t)BB*SS*DD*4);
    float* ff      = (float*)carve((size_t)BB*SS*DFF*4);

    k_embed<<<(BB*SS*DD)/256, 256, 0, stream>>>(x, embW, embB, h);

    for (int l = 0; l < DEPTH; l++) {
        const float* wqk = Wqk + (size_t)l*DD*DD;
        const float* wv  = Wv  + (size_t)l*DD*DD;
        const float* wo  = Wo  + (size_t)l*DD*DD;
        const float* rl  = R   + (size_t)l*HH*DH*NHASH*16;
        const float* g1  = ln1g + l*DD; const float* bg1 = ln1b + l*DD;
        const float* g2  = ln2g + l*DD; const float* bg2 = ln2b + l*DD;
        const float* w1  = W1 + (size_t)l*DD*DFF; const float* bb1 = b1 + l*DFF;
        const float* w2  = W2 + (size_t)l*DFF*DD; const float* bb2 = b2 + l*DD;

        k_proj_qkv<<<(BB*SS)/16, 256, 0, stream>>>(h, g1, bg1, wqk, wv, qk, v);
        k_hash<<<(NBH*NHASH*SS)/256, 256, 0, stream>>>(qk, rl, bkt);
        k_scatter<<<NBH*NHASH, 256, 0, stream>>>(bkt, sticker);
        k_attn<<<NBH*NCHUNK, 256, 0, stream>>>(qk, v, sticker, so, slog);
        k_combine<<<(NBH*SS)/256, 256, 0, stream>>>(so, slog, attn);
        k_wo_res<<<(BB*SS)/16, 256, 0, stream>>>(attn, wo, h);
        k_ff1<<<(BB*SS)/8, 256, 0, stream>>>(h, g2, bg2, w1, bb1, ff);
        k_ff2_res<<<(BB*SS)/16, 256, 0, stream>>>(ff, w2, bb2, h);
    }

    k_final<<<BB, 256, 0, stream>>>(h, fcW, fcb, out);
}